// Round 18
// baseline (306.601 us; speedup 1.0000x reference)
//
#include <hip/hip_runtime.h>
#include <math.h>

#define B_    16
#define C_    256
#define H_    200
#define W_    200
#define NBOX  100
#define HID   256
#define OUTK  7
#define ROI_DIM 12544        // C_ * 49
#define KP    25088          // 2 * ROI_DIM  (2-plane split: [ah,al] x [bh,bh] = a*bh)
#define NCLS  4

struct __attribute__((packed, aligned(4))) f2u { float x, y; };

typedef __attribute__((ext_vector_type(8))) short short8v;
typedef __attribute__((ext_vector_type(4))) float f32x4;

static __device__ __forceinline__ unsigned short f2bf(float f) {
  unsigned u = __float_as_uint(f);
  return (unsigned short)((u + 0x7FFFu + ((u >> 16) & 1u)) >> 16);   // RNE
}
static __device__ __forceinline__ float bf2f(unsigned short h) {
  return __uint_as_float(((unsigned)h) << 16);
}
static __device__ __forceinline__ ushort4 cvt4(float4 v) {
  return make_ushort4(f2bf(v.x), f2bf(v.y), f2bf(v.z), f2bf(v.w));
}

// ---------------------------------------------------------------- K0: per-(img,box,sample) geometry tables
__global__ __launch_bounds__(256) void boxtab_kernel(
    const float* __restrict__ boxes, int2* __restrict__ ytab, int2* __restrict__ xtab)
{
  int t = blockIdx.x * 256 + threadIdx.x;
  if (t >= B_ * NBOX * 14) return;
  int s14 = t % 14;
  int ib  = t / 14;
  const float* bx = boxes + (size_t)ib * 4;
  int i = s14 >> 1, s = s14 & 1;
  float fo = (float)i + 0.25f + 0.5f * (float)s;
  {   // y
    float y1 = bx[1] - 0.5f;
    float bh = (bx[3] - 0.5f - y1) * (1.0f / 7.0f);
    float yc = fminf(fmaxf(y1 + fo * bh, 0.0f), 199.0f);
    int y0 = min((int)yc, 198);
    ytab[(size_t)ib * 14 + s14] = make_int2(y0 * W_, __float_as_int(yc - (float)y0));
  }
  {   // x
    float x1 = bx[0] - 0.5f;
    float bw = (bx[2] - 0.5f - x1) * (1.0f / 7.0f);
    float xc = fminf(fmaxf(x1 + fo * bw, 0.0f), 199.0f);
    int x0 = min((int)xc, 198);
    xtab[(size_t)ib * 14 + s14] = make_int2(x0, __float_as_int(xc - (float)x0));
  }
}

// ---------------------------------------------------------------- K1: ROI align — persistent per-CU block, in-block dbuf overlap
// Block = (img, 16-channel chunk), 1024 threads, 2 x 78.125KB bf16 maps in
// LDS (156.25KB). Per channel: issue next map's 10xfloat4 loads to regs ->
// sched_barrier -> gather current channel from LDS (HBM latency hides under
// ~5us of LDS-gather) -> vmcnt-waited convert+ds_write to other buffer ->
// sync. Stage(104us floor) and gather now overlap BY CONSTRUCTION (R17's
// 2-block scheme measured additive, not overlapped). 256 blocks = 1/CU.
__global__ __launch_bounds__(1024, 4) void roi_pool_kernel(
    const float* __restrict__ feat, const int2* __restrict__ ytab,
    const int2* __restrict__ xtab, unsigned* __restrict__ Ap32)
{
  extern __shared__ unsigned short smem[];   // 2 x 40000 u16 = 160000 B
  unsigned short* buf0 = smem;
  unsigned short* buf1 = smem + 40000;

  int bid = blockIdx.x;              // 256 = 16 img x 16 chunks
  int img = bid >> 4;
  int ch0 = (bid & 15) * 16;
  int tid = threadIdx.x;

  const int4* yt = (const int4*)(ytab + (size_t)img * NBOX * 14);  // {yr0,ly0,yr1,ly1}
  const int4* xt = (const int4*)(xtab + (size_t)img * NBOX * 14);  // {x0,lx0,x1,lx1}
  unsigned* apb = Ap32 + (size_t)img * NBOX * ROI_DIM;

  const float4* fbase = (const float4*)(feat + ((size_t)img * C_ + ch0) * (H_ * W_));

  // prologue: stage channel ch0 -> buf0
  {
    #pragma unroll
    for (int r = 0; r < 9; ++r) {
      int i = tid + r * 1024;
      *(ushort4*)(buf0 + i * 4) = cvt4(fbase[i]);
    }
    int i = tid + 9 * 1024;
    if (i < 10000) *(ushort4*)(buf0 + i * 4) = cvt4(fbase[i]);
  }
  __syncthreads();

  #pragma unroll 1
  for (int n = 0; n < 16; ++n) {
    const unsigned short* cur = (n & 1) ? buf1 : buf0;
    unsigned short*       nxt = (n & 1) ? buf0 : buf1;

    // (a) issue next channel's loads into registers (no wait)
    float4 rv0, rv1, rv2, rv3, rv4, rv5, rv6, rv7, rv8, rv9;
    if (n < 15) {
      const float4* src = fbase + (size_t)(n + 1) * (H_ * W_ / 4);
      rv0 = src[tid];            rv1 = src[tid + 1024];
      rv2 = src[tid + 2048];     rv3 = src[tid + 3072];
      rv4 = src[tid + 4096];     rv5 = src[tid + 5120];
      rv6 = src[tid + 6144];     rv7 = src[tid + 7168];
      rv8 = src[tid + 8192];
      if (tid < 784) rv9 = src[tid + 9216];
    }
    __builtin_amdgcn_sched_barrier(0);

    // (b) gather channel ch0+n from cur
    unsigned* ap = apb + (size_t)(ch0 + n) * 49;
    #pragma unroll
    for (int rnd = 0; rnd < 5; ++rnd) {
      int it = tid + rnd * 1024;
      if (it < NBOX * 49) {
        int box = it / 49;
        int bin = it - box * 49;
        int bi  = bin / 7;
        int bj  = bin - bi * 7;

        int4 yw = yt[box * 7 + bi];
        int4 xw = xt[box * 7 + bj];
        int   yr0 = yw.x, yr1 = yw.z;
        float ly0 = __int_as_float(yw.y), ly1 = __int_as_float(yw.w);
        int   xc0 = xw.x, xc1 = xw.z;
        float lx0 = __int_as_float(xw.y), lx1 = __int_as_float(xw.w);
        float hy0 = 1.0f - ly0, hy1 = 1.0f - ly1;
        float hx0 = 1.0f - lx0, hx1 = 1.0f - lx1;

        int p00 = yr0 + xc0, p01 = yr0 + xc1;
        int p10 = yr0 + W_ + xc0, p11 = yr0 + W_ + xc1;
        int q00 = yr1 + xc0, q01 = yr1 + xc1;
        int q10 = yr1 + W_ + xc0, q11 = yr1 + W_ + xc1;

        float sum =
            hy0 * (hx0 * bf2f(cur[p00]) + lx0 * bf2f(cur[p00 + 1]))
          + ly0 * (hx0 * bf2f(cur[p10]) + lx0 * bf2f(cur[p10 + 1]))
          + hy0 * (hx1 * bf2f(cur[p01]) + lx1 * bf2f(cur[p01 + 1]))
          + ly0 * (hx1 * bf2f(cur[p11]) + lx1 * bf2f(cur[p11 + 1]))
          + hy1 * (hx0 * bf2f(cur[q00]) + lx0 * bf2f(cur[q00 + 1]))
          + ly1 * (hx0 * bf2f(cur[q10]) + lx0 * bf2f(cur[q10 + 1]))
          + hy1 * (hx1 * bf2f(cur[q01]) + lx1 * bf2f(cur[q01 + 1]))
          + ly1 * (hx1 * bf2f(cur[q11]) + lx1 * bf2f(cur[q11 + 1]));

        float s = sum * 0.25f;
        unsigned short hi = f2bf(s);
        unsigned short lo = f2bf(s - bf2f(hi));
        ap[(size_t)box * ROI_DIM + bin] = (unsigned)hi | ((unsigned)lo << 16);
      }
    }
    __builtin_amdgcn_sched_barrier(0);

    // (c) convert + write next map (compiler inserts vmcnt waits before uses)
    if (n < 15) {
      *(ushort4*)(nxt + (tid         ) * 4) = cvt4(rv0);
      *(ushort4*)(nxt + (tid +  1024) * 4) = cvt4(rv1);
      *(ushort4*)(nxt + (tid +  2048) * 4) = cvt4(rv2);
      *(ushort4*)(nxt + (tid +  3072) * 4) = cvt4(rv3);
      *(ushort4*)(nxt + (tid +  4096) * 4) = cvt4(rv4);
      *(ushort4*)(nxt + (tid +  5120) * 4) = cvt4(rv5);
      *(ushort4*)(nxt + (tid +  6144) * 4) = cvt4(rv6);
      *(ushort4*)(nxt + (tid +  7168) * 4) = cvt4(rv7);
      *(ushort4*)(nxt + (tid +  8192) * 4) = cvt4(rv8);
      if (tid < 784) *(ushort4*)(nxt + (tid + 9216) * 4) = cvt4(rv9);
    }
    __syncthreads();
  }
}

// ---------------------------------------------------------------- K1b: w_roi -> B' = [bh, bh] (k-interleaved dup)
__global__ __launch_bounds__(256) void wconv_kernel(
    const float* __restrict__ w, unsigned* __restrict__ Bp32)
{
  int i = blockIdx.x * 256 + threadIdx.x;     // over 256*12544
  unsigned short hi = f2bf(w[i]);
  Bp32[i] = (unsigned)hi | ((unsigned)hi << 16);
}

// ---------------------------------------------------------------- K3: bf16 MFMA GEMM, full-N tile, partials (no atomics)
#define GBM 64
#define GBN 256
#define GBK 64
#define KSP 14
#define KT  28        // (KP/GBK)/KSP = 392/14
__global__ __launch_bounds__(256) void gemm_kernel(
    const unsigned short* __restrict__ Ap,
    const unsigned short* __restrict__ Bp,
    float* __restrict__ Cpart)
{
  __shared__ __align__(16) short As[GBM * GBK];   // 8 KB, swizzled chunks
  __shared__ __align__(16) short Bs[GBN * GBK];   // 32 KB

  int tid  = threadIdx.x;
  int lane = tid & 63;
  int w    = tid >> 6;
  int wr   = w >> 1, wc = w & 1;          // wave: rows wr*32, cols wc*128
  int m0 = blockIdx.x * GBM;
  int z  = blockIdx.y;
  int kbase = z * (GBK * KT);

  f32x4 acc[2][8];
  #pragma unroll
  for (int mi = 0; mi < 2; ++mi)
    #pragma unroll
    for (int nj = 0; nj < 8; ++nj)
      acc[mi][nj] = (f32x4){0.f, 0.f, 0.f, 0.f};

  for (int kt = 0; kt < KT; ++kt) {
    int kg = kbase + kt * GBK;
    __syncthreads();
    #pragma unroll
    for (int r = 0; r < 2; ++r) {          // stage A: 512 chunks of 16B
      int q = tid + r * 256;
      int row = q >> 3, c16 = q & 7;
      int kc16 = c16 ^ (row & 7);
      short8v v = *(const short8v*)(Ap + (size_t)(m0 + row) * KP + kg + kc16 * 8);
      *(short8v*)(As + row * GBK + c16 * 8) = v;
    }
    #pragma unroll
    for (int r = 0; r < 8; ++r) {          // stage B: 2048 chunks (all 256 rows)
      int q = tid + r * 256;
      int row = q >> 3, c16 = q & 7;
      int kc16 = c16 ^ (row & 7);
      short8v v = *(const short8v*)(Bp + (size_t)row * KP + kg + kc16 * 8);
      *(short8v*)(Bs + row * GBK + c16 * 8) = v;
    }
    __syncthreads();
    #pragma unroll
    for (int kk = 0; kk < 2; ++kk) {       // two K=32 steps per tile
      short8v af[2], bf[8];
      #pragma unroll
      for (int mi = 0; mi < 2; ++mi) {
        int row = wr * 32 + mi * 16 + (lane & 15);
        int c16 = (kk * 4 + (lane >> 4)) ^ (row & 7);
        af[mi] = *(const short8v*)(As + row * GBK + c16 * 8);
      }
      #pragma unroll
      for (int nj = 0; nj < 8; ++nj) {
        int row = wc * 128 + nj * 16 + (lane & 15);
        int c16 = (kk * 4 + (lane >> 4)) ^ (row & 7);
        bf[nj] = *(const short8v*)(Bs + row * GBK + c16 * 8);
      }
      #pragma unroll
      for (int mi = 0; mi < 2; ++mi)
        #pragma unroll
        for (int nj = 0; nj < 8; ++nj)
          acc[mi][nj] = __builtin_amdgcn_mfma_f32_16x16x32_bf16(
              af[mi], bf[nj], acc[mi][nj], 0, 0, 0);
    }
  }
  // epilogue: plain stores to partial buffer (D col=lane&15, row=(lane>>4)*4+reg)
  float* part = Cpart + (size_t)z * (B_ * NBOX * HID);
  int cn = lane & 15, rg = lane >> 4;
  #pragma unroll
  for (int mi = 0; mi < 2; ++mi)
    #pragma unroll
    for (int nj = 0; nj < 8; ++nj)
      #pragma unroll
      for (int r = 0; r < 4; ++r) {
        int row = m0 + wr * 32 + mi * 16 + rg * 4 + r;
        int col = wc * 128 + nj * 16 + cn;
        part[(size_t)row * HID + col] = acc[mi][nj][r];
      }
}

// ---------------------------------------------------------------- K3b: tokens = bias + sum of partials (float4)
__global__ __launch_bounds__(256) void reduce_kernel(
    const float* __restrict__ Cpart, const float* __restrict__ b_roi,
    float* __restrict__ tokens)
{
  int i = blockIdx.x * 256 + threadIdx.x;   // over 102400 float4s
  const float4* bias4 = (const float4*)b_roi;
  float4 a = bias4[i & 63];
  const float4* cp = (const float4*)Cpart;
  #pragma unroll
  for (int z = 0; z < KSP; ++z) {
    float4 p = cp[(size_t)z * (B_ * NBOX * HID / 4) + i];
    a.x += p.x; a.y += p.y; a.z += p.z; a.w += p.w;
  }
  ((float4*)tokens)[i] = a;
}

// ---------------------------------------------------------------- K4a: attention per (batch, head) -> ctx
__global__ __launch_bounds__(256) void attn_kernel(
    const float* __restrict__ tokens, const float* __restrict__ sev_q,
    const float* __restrict__ w_in,  const float* __restrict__ b_in,
    float* __restrict__ ctx)
{
  __shared__ float qh_s[64], qkv_s[256], att_s[128], tbar_s[256], red_s[2];
  int bh = blockIdx.x;
  int b = bh >> 2, h = bh & 3;
  int tid = threadIdx.x;
  const float* tok = tokens + (size_t)b * NBOX * HID;

  if (tid < 64) {                      // qh[d] = sev_q . Wq[h*64+d] + bq
    const float* wq = w_in + (size_t)(h * 64 + tid) * HID;
    float a = 0.0f;
    for (int e = 0; e < HID; ++e) a += sev_q[e] * wq[e];
    qh_s[tid] = a + b_in[h * 64 + tid];
  }
  __syncthreads();
  {                                    // qkv[e] = sum_d qh[d] * Wk[h*64+d][e]
    float a = 0.0f;
    for (int d = 0; d < 64; ++d)
      a += qh_s[d] * w_in[(size_t)(256 + h * 64 + d) * HID + tid];
    qkv_s[tid] = a;
  }
  if (tid == 0) {                      // qkb
    float a = 0.0f;
    for (int d = 0; d < 64; ++d) a += qh_s[d] * b_in[256 + h * 64 + d];
    red_s[0] = a;
  }
  __syncthreads();
  if (tid < NBOX) {                    // scores
    const float4* tr = (const float4*)(tok + (size_t)tid * HID);
    const float4* qv = (const float4*)qkv_s;
    float a = 0.0f;
    for (int e = 0; e < 64; ++e) {
      float4 t4 = tr[e], q4 = qv[e];
      a += t4.x * q4.x + t4.y * q4.y + t4.z * q4.z + t4.w * q4.w;
    }
    att_s[tid] = (a + red_s[0]) * 0.125f;
  }
  __syncthreads();
  if (tid == 0) {                      // softmax (serial; 100 elems)
    float mx = -1e30f;
    for (int t = 0; t < NBOX; ++t) mx = fmaxf(mx, att_s[t]);
    float sm = 0.0f;
    for (int t = 0; t < NBOX; ++t) { float e = expf(att_s[t] - mx); att_s[t] = e; sm += e; }
    red_s[1] = 1.0f / sm;
  }
  __syncthreads();
  {                                    // tbar[e] = inv * sum_t att[t]*tok[t][e]
    float a = 0.0f;
    for (int t = 0; t < NBOX; ++t) a += att_s[t] * tok[(size_t)t * HID + tid];
    tbar_s[tid] = a * red_s[1];
  }
  __syncthreads();
  if (tid < 64) {                      // ctx[h*64+d] = tbar . Wv[h*64+d] + bv
    const float* wv = w_in + (size_t)(512 + h * 64 + tid) * HID;
    float a = 0.0f;
    for (int e = 0; e < HID; ++e) a += tbar_s[e] * wv[e];
    ctx[(size_t)b * HID + h * 64 + tid] = a + b_in[512 + h * 64 + tid];
  }
}

// ---------------------------------------------------------------- K4b: Wout + LayerNorm + MLP per batch
__global__ __launch_bounds__(256) void mlp_kernel(
    const float* __restrict__ ctx,
    const float* __restrict__ w_out, const float* __restrict__ b_out,
    const float* __restrict__ ln_g,  const float* __restrict__ ln_b,
    const float* __restrict__ w1,    const float* __restrict__ b1,
    const float* __restrict__ w2,    const float* __restrict__ b2,
    float* __restrict__ outp)
{
  __shared__ float o_s[256], x_s[256], h1_s[256], red_s[8];
  int b = blockIdx.x, tid = threadIdx.x;
  const float* cx = ctx + (size_t)b * HID;
  {
    const float* wo = w_out + (size_t)tid * HID;
    float a = 0.0f;
    for (int k = 0; k < HID; ++k) a += cx[k] * wo[k];
    o_s[tid] = a + b_out[tid];
  }
  __syncthreads();
  {
    float v = o_s[tid];
    float s1 = v, s2 = v * v;
    #pragma unroll
    for (int off = 32; off > 0; off >>= 1) {
      s1 += __shfl_down(s1, off);
      s2 += __shfl_down(s2, off);
    }
    if ((tid & 63) == 0) { red_s[(tid >> 6) * 2] = s1; red_s[(tid >> 6) * 2 + 1] = s2; }
    __syncthreads();
    float sum = red_s[0] + red_s[2] + red_s[4] + red_s[6];
    float ssq = red_s[1] + red_s[3] + red_s[5] + red_s[7];
    float mu  = sum * (1.0f / 256.0f);
    float var = ssq * (1.0f / 256.0f) - mu * mu;
    float inv = rsqrtf(var + 1e-5f);
    x_s[tid] = (v - mu) * inv * ln_g[tid] + ln_b[tid];
  }
  __syncthreads();
  {
    const float* wr = w1 + (size_t)tid * HID;
    float a = 0.0f;
    for (int k = 0; k < HID; ++k) a += x_s[k] * wr[k];
    h1_s[tid] = fmaxf(a + b1[tid], 0.0f);
  }
  __syncthreads();
  if (tid < NCLS) {
    const float* wr = w2 + (size_t)tid * HID;
    float a = 0.0f;
    for (int k = 0; k < HID; ++k) a += h1_s[k] * wr[k];
    outp[b * NCLS + tid] = a + b2[tid];
  }
}

// ---------------------------------------------------------------- launch
extern "C" void kernel_launch(void* const* d_in, const int* in_sizes, int n_in,
                              void* d_out, int out_size, void* d_ws, size_t ws_size,
                              hipStream_t stream) {
  (void)in_sizes; (void)n_in; (void)out_size; (void)ws_size;
  const float* feat  = (const float*)d_in[0];
  const float* boxes = (const float*)d_in[1];
  const float* w_roi = (const float*)d_in[2];
  const float* b_roi = (const float*)d_in[3];
  const float* sev_q = (const float*)d_in[4];
  const float* w_in  = (const float*)d_in[5];
  const float* b_in  = (const float*)d_in[6];
  const float* w_out = (const float*)d_in[7];
  const float* b_out = (const float*)d_in[8];
  const float* ln_g  = (const float*)d_in[9];
  const float* ln_b  = (const float*)d_in[10];
  const float* w1    = (const float*)d_in[11];
  const float* b1    = (const float*)d_in[12];
  const float* w2    = (const float*)d_in[13];
  const float* b2    = (const float*)d_in[14];
  float* out = (float*)d_out;

  unsigned short* Ap = (unsigned short*)d_ws;            // 1600 x 25088 split-bf16
  unsigned short* Bp = Ap + (size_t)B_ * NBOX * KP;      // 256 x 25088
  float* Cpart  = (float*)(Bp + (size_t)HID * KP);       // KSP x 1600 x 256 f32
  float* tokens = Cpart + (size_t)KSP * B_ * NBOX * HID; // 1600 x 256 f32
  float* ctx    = tokens + (size_t)B_ * NBOX * HID;      // 16 x 256 f32
  int2* ytab    = (int2*)(ctx + B_ * HID);               // 1600 x 14 int2
  int2* xtab    = ytab + (size_t)B_ * NBOX * 14;         // 1600 x 14 int2

  boxtab_kernel  <<<(B_ * NBOX * 14 + 255) / 256, 256, 0, stream>>>(boxes, ytab, xtab);
  roi_pool_kernel<<<B_ * 16, 1024, 160000, stream>>>(feat, ytab, xtab, (unsigned*)Ap);
  wconv_kernel   <<<(HID * ROI_DIM) / 256, 256, 0, stream>>>(w_roi, (unsigned*)Bp);
  gemm_kernel    <<<dim3((B_ * NBOX) / GBM, KSP), 256, 0, stream>>>(Ap, Bp, Cpart);
  reduce_kernel  <<<(B_ * NBOX * HID / 4) / 256, 256, 0, stream>>>(Cpart, b_roi, tokens);
  attn_kernel    <<<B_ * 4, 256, 0, stream>>>(tokens, sev_q, w_in, b_in, ctx);
  mlp_kernel     <<<B_, 256, 0, stream>>>(ctx, w_out, b_out, ln_g, ln_b,
                                          w1, b1, w2, b2, out);
}

// Round 19
// 276.480 us; speedup vs baseline: 1.1089x; 1.1089x over previous
//
#include <hip/hip_runtime.h>
#include <math.h>

#define B_    16
#define C_    256
#define H_    200
#define W_    200
#define NBOX  100
#define HID   256
#define OUTK  7
#define ROI_DIM 12544        // C_ * 49
#define KP    25088          // 2 * ROI_DIM  (2-plane split: [ah,al] x [bh,bh] = a*bh)
#define NCLS  4

struct __attribute__((packed, aligned(4))) f2u { float x, y; };

typedef __attribute__((ext_vector_type(8))) short short8v;
typedef __attribute__((ext_vector_type(4))) float f32x4;

static __device__ __forceinline__ unsigned short f2bf(float f) {
  unsigned u = __float_as_uint(f);
  return (unsigned short)((u + 0x7FFFu + ((u >> 16) & 1u)) >> 16);   // RNE
}
static __device__ __forceinline__ float bf2f(unsigned short h) {
  return __uint_as_float(((unsigned)h) << 16);
}

// ---------------------------------------------------------------- K0: per-(img,box,sample) geometry tables
__global__ __launch_bounds__(256) void boxtab_kernel(
    const float* __restrict__ boxes, int2* __restrict__ ytab, int2* __restrict__ xtab)
{
  int t = blockIdx.x * 256 + threadIdx.x;
  if (t >= B_ * NBOX * 14) return;
  int s14 = t % 14;
  int ib  = t / 14;
  const float* bx = boxes + (size_t)ib * 4;
  int i = s14 >> 1, s = s14 & 1;
  float fo = (float)i + 0.25f + 0.5f * (float)s;
  {   // y
    float y1 = bx[1] - 0.5f;
    float bh = (bx[3] - 0.5f - y1) * (1.0f / 7.0f);
    float yc = fminf(fmaxf(y1 + fo * bh, 0.0f), 199.0f);
    int y0 = min((int)yc, 198);
    ytab[(size_t)ib * 14 + s14] = make_int2(y0 * W_, __float_as_int(yc - (float)y0));
  }
  {   // x
    float x1 = bx[0] - 0.5f;
    float bw = (bx[2] - 0.5f - x1) * (1.0f / 7.0f);
    float xc = fminf(fmaxf(x1 + fo * bw, 0.0f), 199.0f);
    int x0 = min((int)xc, 198);
    xtab[(size_t)ib * 14 + s14] = make_int2(x0, __float_as_int(xc - (float)x0));
  }
}

// ---------------------------------------------------------------- K1: ROI align — bf16 channel map in LDS, 2 blocks/CU (R17, best)
// Block = (img, ch), 1024 threads, 78.125 KiB dynamic LDS (bf16 map) ->
// TWO blocks/CU: block n+1's BW-bound stage overlaps block n's gather.
// Gather: 16 ds_read_u16 taps, f32 interp. launch_bounds(1024,8) pins
// VGPR<=64 so 2 blocks co-reside. Measured 276.8us total; 7 structural
// alternatives (async-DMA, stream-interleave, L2-epoch, persistent dbuf,
// wide windows, channel-exclusive) all measured worse or null.
__global__ __launch_bounds__(1024, 8) void roi_pool_kernel(
    const float* __restrict__ feat, const int2* __restrict__ ytab,
    const int2* __restrict__ xtab, unsigned* __restrict__ Ap32)
{
  extern __shared__ unsigned short lmap[];   // 200*200 bf16 = 80000 B
  int bid = blockIdx.x;
  int img = bid >> 8;                 // 0..15
  int ch  = bid & 255;
  int tid = threadIdx.x;

  // ---- phase 1: stage the full channel map as bf16 (10000 float4 -> ushort4)
  const float4* src = (const float4*)(feat + ((size_t)img * C_ + ch) * (H_ * W_));
  #pragma unroll
  for (int r = 0; r < 9; ++r) {
    int i = tid + r * 1024;
    float4 v = src[i];
    ushort4 h = make_ushort4(f2bf(v.x), f2bf(v.y), f2bf(v.z), f2bf(v.w));
    *(ushort4*)(lmap + i * 4) = h;
  }
  {
    int i = tid + 9 * 1024;
    if (i < 10000) {
      float4 v = src[i];
      ushort4 h = make_ushort4(f2bf(v.x), f2bf(v.y), f2bf(v.z), f2bf(v.w));
      *(ushort4*)(lmap + i * 4) = h;
    }
  }
  __syncthreads();

  const int4* yt = (const int4*)(ytab + (size_t)img * NBOX * 14);  // {yr0,ly0,yr1,ly1}
  const int4* xt = (const int4*)(xtab + (size_t)img * NBOX * 14);  // {x0,lx0,x1,lx1}
  unsigned* ap = Ap32 + (size_t)img * NBOX * ROI_DIM + ch * 49;

  // ---- phase 2: gather 100 boxes x 49 bins from LDS (5 rounds)
  #pragma unroll
  for (int rnd = 0; rnd < 5; ++rnd) {
    int it = tid + rnd * 1024;
    if (it < NBOX * 49) {
      int box = it / 49;
      int bin = it - box * 49;
      int bi  = bin / 7;
      int bj  = bin - bi * 7;

      int4 yw = yt[box * 7 + bi];
      int4 xw = xt[box * 7 + bj];
      int   yr0 = yw.x, yr1 = yw.z;
      float ly0 = __int_as_float(yw.y), ly1 = __int_as_float(yw.w);
      int   xc0 = xw.x, xc1 = xw.z;
      float lx0 = __int_as_float(xw.y), lx1 = __int_as_float(xw.w);
      float hy0 = 1.0f - ly0, hy1 = 1.0f - ly1;
      float hx0 = 1.0f - lx0, hx1 = 1.0f - lx1;

      int p00 = yr0 + xc0, p01 = yr0 + xc1;
      int p10 = yr0 + W_ + xc0, p11 = yr0 + W_ + xc1;
      int q00 = yr1 + xc0, q01 = yr1 + xc1;
      int q10 = yr1 + W_ + xc0, q11 = yr1 + W_ + xc1;

      float sum =
          hy0 * (hx0 * bf2f(lmap[p00]) + lx0 * bf2f(lmap[p00 + 1]))
        + ly0 * (hx0 * bf2f(lmap[p10]) + lx0 * bf2f(lmap[p10 + 1]))
        + hy0 * (hx1 * bf2f(lmap[p01]) + lx1 * bf2f(lmap[p01 + 1]))
        + ly0 * (hx1 * bf2f(lmap[p11]) + lx1 * bf2f(lmap[p11 + 1]))
        + hy1 * (hx0 * bf2f(lmap[q00]) + lx0 * bf2f(lmap[q00 + 1]))
        + ly1 * (hx0 * bf2f(lmap[q10]) + lx0 * bf2f(lmap[q10 + 1]))
        + hy1 * (hx1 * bf2f(lmap[q01]) + lx1 * bf2f(lmap[q01 + 1]))
        + ly1 * (hx1 * bf2f(lmap[q11]) + lx1 * bf2f(lmap[q11 + 1]));

      float s = sum * 0.25f;
      unsigned short hi = f2bf(s);
      unsigned short lo = f2bf(s - bf2f(hi));
      ap[(size_t)box * ROI_DIM + bin] = (unsigned)hi | ((unsigned)lo << 16);
    }
  }
}

// ---------------------------------------------------------------- K1b: w_roi -> B' = [bh, bh] (k-interleaved dup)
__global__ __launch_bounds__(256) void wconv_kernel(
    const float* __restrict__ w, unsigned* __restrict__ Bp32)
{
  int i = blockIdx.x * 256 + threadIdx.x;     // over 256*12544
  unsigned short hi = f2bf(w[i]);
  Bp32[i] = (unsigned)hi | ((unsigned)hi << 16);
}

// ---------------------------------------------------------------- K3: bf16 MFMA GEMM, full-N tile, partials (no atomics)
#define GBM 64
#define GBN 256
#define GBK 64
#define KSP 14
#define KT  28        // (KP/GBK)/KSP = 392/14
__global__ __launch_bounds__(256) void gemm_kernel(
    const unsigned short* __restrict__ Ap,
    const unsigned short* __restrict__ Bp,
    float* __restrict__ Cpart)
{
  __shared__ __align__(16) short As[GBM * GBK];   // 8 KB, swizzled chunks
  __shared__ __align__(16) short Bs[GBN * GBK];   // 32 KB

  int tid  = threadIdx.x;
  int lane = tid & 63;
  int w    = tid >> 6;
  int wr   = w >> 1, wc = w & 1;          // wave: rows wr*32, cols wc*128
  int m0 = blockIdx.x * GBM;
  int z  = blockIdx.y;
  int kbase = z * (GBK * KT);

  f32x4 acc[2][8];
  #pragma unroll
  for (int mi = 0; mi < 2; ++mi)
    #pragma unroll
    for (int nj = 0; nj < 8; ++nj)
      acc[mi][nj] = (f32x4){0.f, 0.f, 0.f, 0.f};

  for (int kt = 0; kt < KT; ++kt) {
    int kg = kbase + kt * GBK;
    __syncthreads();
    #pragma unroll
    for (int r = 0; r < 2; ++r) {          // stage A: 512 chunks of 16B
      int q = tid + r * 256;
      int row = q >> 3, c16 = q & 7;
      int kc16 = c16 ^ (row & 7);
      short8v v = *(const short8v*)(Ap + (size_t)(m0 + row) * KP + kg + kc16 * 8);
      *(short8v*)(As + row * GBK + c16 * 8) = v;
    }
    #pragma unroll
    for (int r = 0; r < 8; ++r) {          // stage B: 2048 chunks (all 256 rows)
      int q = tid + r * 256;
      int row = q >> 3, c16 = q & 7;
      int kc16 = c16 ^ (row & 7);
      short8v v = *(const short8v*)(Bp + (size_t)row * KP + kg + kc16 * 8);
      *(short8v*)(Bs + row * GBK + c16 * 8) = v;
    }
    __syncthreads();
    #pragma unroll
    for (int kk = 0; kk < 2; ++kk) {       // two K=32 steps per tile
      short8v af[2], bf[8];
      #pragma unroll
      for (int mi = 0; mi < 2; ++mi) {
        int row = wr * 32 + mi * 16 + (lane & 15);
        int c16 = (kk * 4 + (lane >> 4)) ^ (row & 7);
        af[mi] = *(const short8v*)(As + row * GBK + c16 * 8);
      }
      #pragma unroll
      for (int nj = 0; nj < 8; ++nj) {
        int row = wc * 128 + nj * 16 + (lane & 15);
        int c16 = (kk * 4 + (lane >> 4)) ^ (row & 7);
        bf[nj] = *(const short8v*)(Bs + row * GBK + c16 * 8);
      }
      #pragma unroll
      for (int mi = 0; mi < 2; ++mi)
        #pragma unroll
        for (int nj = 0; nj < 8; ++nj)
          acc[mi][nj] = __builtin_amdgcn_mfma_f32_16x16x32_bf16(
              af[mi], bf[nj], acc[mi][nj], 0, 0, 0);
    }
  }
  // epilogue: plain stores to partial buffer (D col=lane&15, row=(lane>>4)*4+reg)
  float* part = Cpart + (size_t)z * (B_ * NBOX * HID);
  int cn = lane & 15, rg = lane >> 4;
  #pragma unroll
  for (int mi = 0; mi < 2; ++mi)
    #pragma unroll
    for (int nj = 0; nj < 8; ++nj)
      #pragma unroll
      for (int r = 0; r < 4; ++r) {
        int row = m0 + wr * 32 + mi * 16 + rg * 4 + r;
        int col = wc * 128 + nj * 16 + cn;
        part[(size_t)row * HID + col] = acc[mi][nj][r];
      }
}

// ---------------------------------------------------------------- K3b: tokens = bias + sum of partials (float4)
__global__ __launch_bounds__(256) void reduce_kernel(
    const float* __restrict__ Cpart, const float* __restrict__ b_roi,
    float* __restrict__ tokens)
{
  int i = blockIdx.x * 256 + threadIdx.x;   // over 102400 float4s
  const float4* bias4 = (const float4*)b_roi;
  float4 a = bias4[i & 63];
  const float4* cp = (const float4*)Cpart;
  #pragma unroll
  for (int z = 0; z < KSP; ++z) {
    float4 p = cp[(size_t)z * (B_ * NBOX * HID / 4) + i];
    a.x += p.x; a.y += p.y; a.z += p.z; a.w += p.w;
  }
  ((float4*)tokens)[i] = a;
}

// ---------------------------------------------------------------- K4a: attention per (batch, head) -> ctx
__global__ __launch_bounds__(256) void attn_kernel(
    const float* __restrict__ tokens, const float* __restrict__ sev_q,
    const float* __restrict__ w_in,  const float* __restrict__ b_in,
    float* __restrict__ ctx)
{
  __shared__ float qh_s[64], qkv_s[256], att_s[128], tbar_s[256], red_s[2];
  int bh = blockIdx.x;
  int b = bh >> 2, h = bh & 3;
  int tid = threadIdx.x;
  const float* tok = tokens + (size_t)b * NBOX * HID;

  if (tid < 64) {                      // qh[d] = sev_q . Wq[h*64+d] + bq
    const float* wq = w_in + (size_t)(h * 64 + tid) * HID;
    float a = 0.0f;
    for (int e = 0; e < HID; ++e) a += sev_q[e] * wq[e];
    qh_s[tid] = a + b_in[h * 64 + tid];
  }
  __syncthreads();
  {                                    // qkv[e] = sum_d qh[d] * Wk[h*64+d][e]
    float a = 0.0f;
    for (int d = 0; d < 64; ++d)
      a += qh_s[d] * w_in[(size_t)(256 + h * 64 + d) * HID + tid];
    qkv_s[tid] = a;
  }
  if (tid == 0) {                      // qkb
    float a = 0.0f;
    for (int d = 0; d < 64; ++d) a += qh_s[d] * b_in[256 + h * 64 + d];
    red_s[0] = a;
  }
  __syncthreads();
  if (tid < NBOX) {                    // scores
    const float4* tr = (const float4*)(tok + (size_t)tid * HID);
    const float4* qv = (const float4*)qkv_s;
    float a = 0.0f;
    for (int e = 0; e < 64; ++e) {
      float4 t4 = tr[e], q4 = qv[e];
      a += t4.x * q4.x + t4.y * q4.y + t4.z * q4.z + t4.w * q4.w;
    }
    att_s[tid] = (a + red_s[0]) * 0.125f;
  }
  __syncthreads();
  if (tid == 0) {                      // softmax (serial; 100 elems)
    float mx = -1e30f;
    for (int t = 0; t < NBOX; ++t) mx = fmaxf(mx, att_s[t]);
    float sm = 0.0f;
    for (int t = 0; t < NBOX; ++t) { float e = expf(att_s[t] - mx); att_s[t] = e; sm += e; }
    red_s[1] = 1.0f / sm;
  }
  __syncthreads();
  {                                    // tbar[e] = inv * sum_t att[t]*tok[t][e]
    float a = 0.0f;
    for (int t = 0; t < NBOX; ++t) a += att_s[t] * tok[(size_t)t * HID + tid];
    tbar_s[tid] = a * red_s[1];
  }
  __syncthreads();
  if (tid < 64) {                      // ctx[h*64+d] = tbar . Wv[h*64+d] + bv
    const float* wv = w_in + (size_t)(512 + h * 64 + tid) * HID;
    float a = 0.0f;
    for (int e = 0; e < HID; ++e) a += tbar_s[e] * wv[e];
    ctx[(size_t)b * HID + h * 64 + tid] = a + b_in[512 + h * 64 + tid];
  }
}

// ---------------------------------------------------------------- K4b: Wout + LayerNorm + MLP per batch
__global__ __launch_bounds__(256) void mlp_kernel(
    const float* __restrict__ ctx,
    const float* __restrict__ w_out, const float* __restrict__ b_out,
    const float* __restrict__ ln_g,  const float* __restrict__ ln_b,
    const float* __restrict__ w1,    const float* __restrict__ b1,
    const float* __restrict__ w2,    const float* __restrict__ b2,
    float* __restrict__ outp)
{
  __shared__ float o_s[256], x_s[256], h1_s[256], red_s[8];
  int b = blockIdx.x, tid = threadIdx.x;
  const float* cx = ctx + (size_t)b * HID;
  {
    const float* wo = w_out + (size_t)tid * HID;
    float a = 0.0f;
    for (int k = 0; k < HID; ++k) a += cx[k] * wo[k];
    o_s[tid] = a + b_out[tid];
  }
  __syncthreads();
  {
    float v = o_s[tid];
    float s1 = v, s2 = v * v;
    #pragma unroll
    for (int off = 32; off > 0; off >>= 1) {
      s1 += __shfl_down(s1, off);
      s2 += __shfl_down(s2, off);
    }
    if ((tid & 63) == 0) { red_s[(tid >> 6) * 2] = s1; red_s[(tid >> 6) * 2 + 1] = s2; }
    __syncthreads();
    float sum = red_s[0] + red_s[2] + red_s[4] + red_s[6];
    float ssq = red_s[1] + red_s[3] + red_s[5] + red_s[7];
    float mu  = sum * (1.0f / 256.0f);
    float var = ssq * (1.0f / 256.0f) - mu * mu;
    float inv = rsqrtf(var + 1e-5f);
    x_s[tid] = (v - mu) * inv * ln_g[tid] + ln_b[tid];
  }
  __syncthreads();
  {
    const float* wr = w1 + (size_t)tid * HID;
    float a = 0.0f;
    for (int k = 0; k < HID; ++k) a += x_s[k] * wr[k];
    h1_s[tid] = fmaxf(a + b1[tid], 0.0f);
  }
  __syncthreads();
  if (tid < NCLS) {
    const float* wr = w2 + (size_t)tid * HID;
    float a = 0.0f;
    for (int k = 0; k < HID; ++k) a += h1_s[k] * wr[k];
    outp[b * NCLS + tid] = a + b2[tid];
  }
}

// ---------------------------------------------------------------- launch
extern "C" void kernel_launch(void* const* d_in, const int* in_sizes, int n_in,
                              void* d_out, int out_size, void* d_ws, size_t ws_size,
                              hipStream_t stream) {
  (void)in_sizes; (void)n_in; (void)out_size; (void)ws_size;
  const float* feat  = (const float*)d_in[0];
  const float* boxes = (const float*)d_in[1];
  const float* w_roi = (const float*)d_in[2];
  const float* b_roi = (const float*)d_in[3];
  const float* sev_q = (const float*)d_in[4];
  const float* w_in  = (const float*)d_in[5];
  const float* b_in  = (const float*)d_in[6];
  const float* w_out = (const float*)d_in[7];
  const float* b_out = (const float*)d_in[8];
  const float* ln_g  = (const float*)d_in[9];
  const float* ln_b  = (const float*)d_in[10];
  const float* w1    = (const float*)d_in[11];
  const float* b1    = (const float*)d_in[12];
  const float* w2    = (const float*)d_in[13];
  const float* b2    = (const float*)d_in[14];
  float* out = (float*)d_out;

  unsigned short* Ap = (unsigned short*)d_ws;            // 1600 x 25088 split-bf16
  unsigned short* Bp = Ap + (size_t)B_ * NBOX * KP;      // 256 x 25088
  float* Cpart  = (float*)(Bp + (size_t)HID * KP);       // KSP x 1600 x 256 f32
  float* tokens = Cpart + (size_t)KSP * B_ * NBOX * HID; // 1600 x 256 f32
  float* ctx    = tokens + (size_t)B_ * NBOX * HID;      // 16 x 256 f32
  int2* ytab    = (int2*)(ctx + B_ * HID);               // 1600 x 14 int2
  int2* xtab    = ytab + (size_t)B_ * NBOX * 14;         // 1600 x 14 int2

  boxtab_kernel  <<<(B_ * NBOX * 14 + 255) / 256, 256, 0, stream>>>(boxes, ytab, xtab);
  roi_pool_kernel<<<B_ * C_, 1024, 80000, stream>>>(feat, ytab, xtab, (unsigned*)Ap);
  wconv_kernel   <<<(HID * ROI_DIM) / 256, 256, 0, stream>>>(w_roi, (unsigned*)Bp);
  gemm_kernel    <<<dim3((B_ * NBOX) / GBM, KSP), 256, 0, stream>>>(Ap, Bp, Cpart);
  reduce_kernel  <<<(B_ * NBOX * HID / 4) / 256, 256, 0, stream>>>(Cpart, b_roi, tokens);
  attn_kernel    <<<B_ * 4, 256, 0, stream>>>(tokens, sev_q, w_in, b_in, ctx);
  mlp_kernel     <<<B_, 256, 0, stream>>>(ctx, w_out, b_out, ln_g, ln_b,
                                          w1, b1, w2, b2, out);
}